// Round 5
// baseline (3370.592 us; speedup 1.0000x reference)
//
#include <hip/hip_runtime.h>
#include <cstdint>
#include <cstddef>

#define TT 512
#define BB 64
#define II 256
#define HH 512
#define GG 1536   // 3*H
#define OO 64
#define NWG 256   // scan workgroups: one per CU (forced by LDS ballast)
#define TAGPAD 16 // dwords between tags (64B -> distinct LLC lines)

// ---------------- Phase A: x_proj (unchanged) ----------------
__global__ __launch_bounds__(256)
void xproj_kernel(const float* __restrict__ x, const float* __restrict__ w,
                  const float* __restrict__ xb, float* __restrict__ xp)
{
    __shared__ float xs[64][68];
    __shared__ float ws[64][68];
    const int t  = blockIdx.y;
    const int g0 = blockIdx.x * 64;
    const int tid = threadIdx.x;
    const int gq = tid >> 4;
    const int bq = tid & 15;
    float acc[4][4];
#pragma unroll
    for (int j = 0; j < 4; ++j)
#pragma unroll
        for (int i = 0; i < 4; ++i) acc[j][i] = 0.f;

    for (int kc = 0; kc < 4; ++kc) {
        const int k0 = kc * 64;
        __syncthreads();
        for (int idx = tid; idx < 1024; idx += 256) {
            int r = idx >> 4, c4 = (idx & 15) * 4;
            float4 v = *(const float4*)(x + ((size_t)t * BB + r) * II + k0 + c4);
            xs[r][c4] = v.x; xs[r][c4+1] = v.y; xs[r][c4+2] = v.z; xs[r][c4+3] = v.w;
            float4 u = *(const float4*)(w + (size_t)(g0 + r) * II + k0 + c4);
            ws[r][c4] = u.x; ws[r][c4+1] = u.y; ws[r][c4+2] = u.z; ws[r][c4+3] = u.w;
        }
        __syncthreads();
#pragma unroll 4
        for (int k4 = 0; k4 < 16; ++k4) {
            float4 xv[4], wv[4];
#pragma unroll
            for (int i = 0; i < 4; ++i)
                xv[i] = *(const float4*)&xs[bq + 16*i][k4*4];
#pragma unroll
            for (int j = 0; j < 4; ++j)
                wv[j] = *(const float4*)&ws[gq + 16*j][k4*4];
#pragma unroll
            for (int j = 0; j < 4; ++j)
#pragma unroll
                for (int i = 0; i < 4; ++i) {
                    acc[j][i] = fmaf(wv[j].x, xv[i].x, acc[j][i]);
                    acc[j][i] = fmaf(wv[j].y, xv[i].y, acc[j][i]);
                    acc[j][i] = fmaf(wv[j].z, xv[i].z, acc[j][i]);
                    acc[j][i] = fmaf(wv[j].w, xv[i].w, acc[j][i]);
                }
        }
    }
#pragma unroll
    for (int j = 0; j < 4; ++j) {
        int g = g0 + gq + 16*j;
        float bg = xb[g];
#pragma unroll
        for (int i = 0; i < 4; ++i) {
            int b = bq + 16*i;
            xp[((size_t)t * GG + g) * BB + b] = acc[j][i] + bg;
        }
    }
}

// ---------------- Phase B: XCD-local persistent GRU scan ----------------
// 1024 threads = 16 waves/CU. Wave = (cp,bh): cols {rk*16+2cp,+1}, local b
// [4bh,4bh+4). Per-step protocol (ONE barrier):
//   xp prefetch -> wave0 lanes 0..31 poll the 32 per-WG tags (LLC, sc0 sc1;
//   ONE lane per tag line -> 32 pollers/line across the XCD, round-2-proven
//   fan-in; round-4's 1024 pollers/line congested the LLC) -> lane0 writes
//   monotonic LDS flag -> other waves spin on LDS (broadcast, no fabric
//   traffic) -> all stage into hlds[t&1] -> __syncthreads -> matvec+reduce
//   -> epilogue store (plain -> XCD L2) -> per-wave vmcnt(0) drain -> lane0
//   bumps LDS counter; 16th arriver releases this WG's tag = t+1 (sc0 sc1,
//   LLC). Tags MUST stay LLC-scope (round-3 failure: L2-scope tags go
//   stale-dirty across bench iterations).
// Transpose-reduce with lane-permuted loads (rows r0=2s1+s0, r1=r0^2,
// r2=r0^1, r3=r0^3; weight col ^s2): keep/send slots position-static ->
// zero cndmask. Output mapping (b=4bh+(l&3), col=c0w+s2) unchanged.
// Group id = HW_REG_XCC_ID; rank via LLC atomic; ballast -> 1 WG/CU.
__global__ __launch_bounds__(1024, 4)
void scan_kernel(const float* __restrict__ xp, const float* __restrict__ hw,
                 const float* __restrict__ hbias, float* __restrict__ rnn,
                 int* __restrict__ tags)
{
    __shared__ float hlds[2][8][512];   // double-buffered h(t-1), 32KB
    __shared__ float pad_[12544];       // ballast: total ~82.9KB -> 1 WG/CU
    __shared__ int s_rk;
    __shared__ int s_cnt;               // monotonic release counter
    __shared__ int s_flag;              // monotonic "step t h ready" flag

    const int tid = threadIdx.x;
    ((volatile float*)pad_)[tid] = 0.f;   // keep ballast allocated

    int xcc;
    asm volatile("s_getreg_b32 %0, hwreg(HW_REG_XCC_ID)" : "=s"(xcc));
    const int g = xcc & 7;               // group = physical XCD
    if (tid == 0) {
        __threadfence();                 // one-time: drop stale/poison lines
        s_cnt = 0;
        s_flag = 0;
        s_rk = atomicAdd(tags + NWG * TAGPAD + g * 16, 1); // rank in XCD
    }
    __syncthreads();
    const int rk = s_rk;
    if (rk >= 32) return;                // cannot happen with 1 WG/CU

    const int w    = tid >> 6;           // wave 0..15
    const int l    = tid & 63;           // lane
    const int cp   = w >> 1;             // column pair 0..7
    const int bh   = w & 1;              // batch half 0..1
    const int c0w  = rk * 16 + 2 * cp;   // wave's first column
    const int s0 = l & 1, s1 = (l >> 1) & 1, s2 = (l >> 2) & 1;
    const int col  = c0w + s2;                 // epilogue column (lanes l<8)
    const int ob   = 8 * g + 4 * bh + (l & 3); // epilogue batch row (global)

    // staging map: thread stages 4 contiguous floats of h(t-1)
    const int sb = tid >> 7;             // local batch row 0..7
    const int sk = (tid & 127) * 4;      // k offset
    const int soff = sb * 512 + sk;      // LDS float offset within buffer

    // wave0 poll target: lane l polls rank l's tag
    const int* tpoll = tags + ((size_t)g * 32 + (l & 31)) * TAGPAD;
    int* tagme       = (int*)(tags + ((size_t)g * 32 + rk) * TAGPAD);

    // lane-permuted rows for cndmask-free transpose-reduce
    const int r0 = 2*s1 + s0, r1 = r0 ^ 2, r2 = r0 ^ 1, r3 = r0 ^ 3;
    float* hflat = &hlds[0][0][0];
    const int roff0 = (4*bh + r0) * 512 + 4*l;
    const int roff1 = (4*bh + r1) * 512 + 4*l;
    const int roff2 = (4*bh + r2) * 512 + 4*l;
    const int roff3 = (4*bh + r3) * 512 + 4*l;

    // weights -> registers: slot rr=2*gate+cslot, col = c0w + (cslot ^ s2)
    float wreg[6][8];
#pragma unroll
    for (int rr = 0; rr < 6; ++rr) {
        const float* wp = hw + ((size_t)(rr >> 1) * HH + c0w + ((rr & 1) ^ s2)) * HH;
        float4 a = *(const float4*)(wp + 4 * l);
        float4 b = *(const float4*)(wp + 256 + 4 * l);
        wreg[rr][0] = a.x; wreg[rr][1] = a.y; wreg[rr][2] = a.z; wreg[rr][3] = a.w;
        wreg[rr][4] = b.x; wreg[rr][5] = b.y; wreg[rr][6] = b.z; wreg[rr][7] = b.w;
    }
    const float bhr = hbias[col];
    const float bhu = hbias[HH + col];
    const float bhn = hbias[2 * HH + col];

    // running pointers (advanced once per step)
    const float* xpr = xp + (size_t)(0 * HH + col) * BB + ob;
    const float* xpu = xp + (size_t)(1 * HH + col) * BB + ob;
    const float* xpn = xp + (size_t)(2 * HH + col) * BB + ob;
    const float* hsp = rnn + (size_t)(8 * g + sb) * HH + sk;   // rnn[t-1] row
    float*       dst = rnn + (size_t)ob * HH + col;            // rnn[t] out

    float hloc = 0.f;            // lanes l<8: my (b,c) previous h (exact fp32)
    long long budget = 4000000;  // spin bound: bug -> wrong answer, not hang

    volatile int* vflag = &s_flag;

    for (int t = 0; t < TT; ++t) {
        // xp prefetch (before poll: completes while we wait on tags/flag)
        float xr = 0.f, xu = 0.f, xn = 0.f;
        if (l < 8) { xr = *xpr; xu = *xpu; xn = *xpn; }

        float g0v = 0.f, g1v = 0.f, g2v = 0.f;
        if (t > 0) {
            // wave0: lanes 0..31 poll the 32 group tags (1 line per lane)
            if (tid < 64) {
                if (l < 32) {
                    int v;
                    do {
                        asm volatile("global_load_dword %0, %1, off sc0 sc1\n\t"
                                     "s_waitcnt vmcnt(0)"
                                     : "=v"(v) : "v"(tpoll) : "memory");
                        if (v >= t) break;
                        __builtin_amdgcn_s_sleep(1);
                    } while (--budget > 0);
                }
                // wave proceeds only when ALL its polling lanes exited
                if (tid == 0) *vflag = t;
            }
            // all waves: spin on LDS flag (wave0 passes immediately)
            {
                long long b2 = 4000000;
                while (*vflag < t) {
                    if (--b2 <= 0) break;
                    __builtin_amdgcn_s_sleep(1);
                }
            }
            // stage my float4 of h(t-1) into buffer t&1 (from XCD L2)
            {
                float4 hv = *(const float4*)hsp;
                *(float4*)(hflat + (t & 1) * 4096 + soff) = hv;
            }
            hsp += BB * HH;
            __syncthreads();     // the ONLY barrier: staging -> compute

            // matvec with permuted rows: 4 b x 6 slots x 8 k = 192 FMA
            const float* hb = hflat + (t & 1) * 4096;
            float4 hA0 = *(const float4*)(hb + roff0), hB0 = *(const float4*)(hb + roff0 + 256);
            float4 hA1 = *(const float4*)(hb + roff1), hB1 = *(const float4*)(hb + roff1 + 256);
            float4 hA2 = *(const float4*)(hb + roff2), hB2 = *(const float4*)(hb + roff2 + 256);
            float4 hA3 = *(const float4*)(hb + roff3), hB3 = *(const float4*)(hb + roff3 + 256);
            float accA[6], accB[6], accC[6], accD[6];
#pragma unroll
            for (int rr = 0; rr < 6; ++rr) {
                float a;
                a = hA0.x * wreg[rr][0];
                a = fmaf(hA0.y, wreg[rr][1], a); a = fmaf(hA0.z, wreg[rr][2], a);
                a = fmaf(hA0.w, wreg[rr][3], a); a = fmaf(hB0.x, wreg[rr][4], a);
                a = fmaf(hB0.y, wreg[rr][5], a); a = fmaf(hB0.z, wreg[rr][6], a);
                a = fmaf(hB0.w, wreg[rr][7], a);
                accA[rr] = a;
                a = hA1.x * wreg[rr][0];
                a = fmaf(hA1.y, wreg[rr][1], a); a = fmaf(hA1.z, wreg[rr][2], a);
                a = fmaf(hA1.w, wreg[rr][3], a); a = fmaf(hB1.x, wreg[rr][4], a);
                a = fmaf(hB1.y, wreg[rr][5], a); a = fmaf(hB1.z, wreg[rr][6], a);
                a = fmaf(hB1.w, wreg[rr][7], a);
                accB[rr] = a;
                a = hA2.x * wreg[rr][0];
                a = fmaf(hA2.y, wreg[rr][1], a); a = fmaf(hA2.z, wreg[rr][2], a);
                a = fmaf(hA2.w, wreg[rr][3], a); a = fmaf(hB2.x, wreg[rr][4], a);
                a = fmaf(hB2.y, wreg[rr][5], a); a = fmaf(hB2.z, wreg[rr][6], a);
                a = fmaf(hB2.w, wreg[rr][7], a);
                accC[rr] = a;
                a = hA3.x * wreg[rr][0];
                a = fmaf(hA3.y, wreg[rr][1], a); a = fmaf(hA3.z, wreg[rr][2], a);
                a = fmaf(hA3.w, wreg[rr][3], a); a = fmaf(hB3.x, wreg[rr][4], a);
                a = fmaf(hB3.y, wreg[rr][5], a); a = fmaf(hB3.z, wreg[rr][6], a);
                a = fmaf(hB3.w, wreg[rr][7], a);
                accD[rr] = a;
            }

            // cndmask-free transpose-reduce
            float t0[6], t1[6], a2[6], a3[3];
#pragma unroll
            for (int rr = 0; rr < 6; ++rr) {
                t0[rr] = accA[rr] + __shfl_xor(accC[rr], 1, 64);
                t1[rr] = accB[rr] + __shfl_xor(accD[rr], 1, 64);
            }
#pragma unroll
            for (int rr = 0; rr < 6; ++rr)
                a2[rr] = t0[rr] + __shfl_xor(t1[rr], 2, 64);
#pragma unroll
            for (int gt = 0; gt < 3; ++gt)
                a3[gt] = a2[2*gt] + __shfl_xor(a2[2*gt + 1], 4, 64);
            g0v = a3[0]; g1v = a3[1]; g2v = a3[2];
            g0v += __shfl_xor(g0v, 8, 64); g0v += __shfl_xor(g0v, 16, 64); g0v += __shfl_xor(g0v, 32, 64);
            g1v += __shfl_xor(g1v, 8, 64); g1v += __shfl_xor(g1v, 16, 64); g1v += __shfl_xor(g1v, 32, 64);
            g2v += __shfl_xor(g2v, 8, 64); g2v += __shfl_xor(g2v, 16, 64); g2v += __shfl_xor(g2v, 32, 64);
        }

        if (l < 8) { // one lane per output (b=ob, c=col)
            float rg = 1.f / (1.f + __expf(-(xr + g0v + bhr)));
            float ug = 1.f / (1.f + __expf(-(xu + g1v + bhu)));
            // h2h bias of n-gate sits INSIDE reset*(...), per reference
            float npre = xn + rg * (g2v + bhn);
            float e  = __expf(-2.f * npre);
            float nv = 2.f / (1.f + e) - 1.f;
            float hy = ug * hloc + (1.f - ug) * nv;
            hloc = hy;
            // plain store: write-through into this XCD's L2
            asm volatile("global_store_dword %0, %1, off"
                         :: "v"(dst), "v"(hy) : "memory");
        }
        // per-wave drain, then non-blocking WG-aggregated release
        asm volatile("s_waitcnt vmcnt(0)" ::: "memory");
        if (l == 0) {
            int old = atomicAdd(&s_cnt, 1);
            if (old == 16 * t + 15) {    // last wave of this WG for step t
                int tv = t + 1;
                asm volatile("global_store_dword %0, %1, off sc0 sc1"
                             :: "v"(tagme), "v"(tv) : "memory");
            }
        }
        xpr += GG * BB; xpu += GG * BB; xpn += GG * BB;
        dst += BB * HH;
    }
}

// ---------------- Phase C: fc output (unchanged) ----------------
__global__ __launch_bounds__(256)
void fc_kernel(const float* __restrict__ rnn, const float* __restrict__ fcw,
               const float* __restrict__ fcb, float* __restrict__ out)
{
    __shared__ float wlds[128][65];
    const int t = blockIdx.x;
    const int tid = threadIdx.x;
    const int o  = tid & 63;
    const int bg = tid >> 6;
    float acc[16];
#pragma unroll
    for (int i = 0; i < 16; ++i) acc[i] = 0.f;

    for (int kc = 0; kc < 4; ++kc) {
        const int k0 = kc * 128;
        __syncthreads();
        for (int idx = tid; idx < 64 * 32; idx += 256) {
            int oo = idx >> 5, kq = (idx & 31) * 4;
            float4 v = *(const float4*)(fcw + (size_t)oo * HH + k0 + kq);
            wlds[kq][oo] = v.x; wlds[kq+1][oo] = v.y;
            wlds[kq+2][oo] = v.z; wlds[kq+3][oo] = v.w;
        }
        __syncthreads();
#pragma unroll 2
        for (int k4 = 0; k4 < 32; ++k4) {
            float w0 = wlds[k4*4+0][o], w1 = wlds[k4*4+1][o];
            float w2 = wlds[k4*4+2][o], w3 = wlds[k4*4+3][o];
#pragma unroll
            for (int i = 0; i < 16; ++i) {
                int bb = bg * 16 + i;
                float4 h4 = *(const float4*)(rnn + ((size_t)t * BB + bb) * HH + k0 + k4*4);
                acc[i] = fmaf(h4.x, w0, fmaf(h4.y, w1, fmaf(h4.z, w2, fmaf(h4.w, w3, acc[i]))));
            }
        }
    }
    float bo = fcb[o];
#pragma unroll
    for (int i = 0; i < 16; ++i) {
        int bb = bg * 16 + i;
        out[((size_t)t * BB + bb) * OO + o] = acc[i] + bo;
    }
}

extern "C" void kernel_launch(void* const* d_in, const int* in_sizes, int n_in,
                              void* d_out, int out_size, void* d_ws, size_t ws_size,
                              hipStream_t stream)
{
    const float* x     = (const float*)d_in[0];
    const float* x2h_w = (const float*)d_in[1];
    const float* x2h_b = (const float*)d_in[2];
    const float* h2h_w = (const float*)d_in[3];
    const float* h2h_b = (const float*)d_in[4];
    const float* fc_w  = (const float*)d_in[5];
    const float* fc_b  = (const float*)d_in[6];

    float* out = (float*)d_out;                        // [T][B][O]
    float* rnn = (float*)d_out + (size_t)TT * BB * OO; // [T][B][H]

    float* xp = (float*)d_ws;                          // [T][3H][B] fp32
    const size_t xp_bytes = (size_t)TT * GG * BB * sizeof(float);
    int* tags = (int*)((char*)d_ws + xp_bytes);        // 256 WG tags + rank ctrs

    hipMemsetAsync(tags, 0, (NWG * TAGPAD + 8 * 16) * sizeof(int), stream);

    dim3 gA(GG / 64, TT);
    xproj_kernel<<<gA, 256, 0, stream>>>(x, x2h_w, x2h_b, xp);
    scan_kernel<<<NWG, 1024, 0, stream>>>(xp, h2h_w, h2h_b, rnn, tags);
    fc_kernel<<<TT, 256, 0, stream>>>(rnn, fc_w, fc_b, out);
}

// Round 7
// 2465.054 us; speedup vs baseline: 1.3674x; 1.3674x over previous
//
#include <hip/hip_runtime.h>
#include <cstdint>
#include <cstddef>

#define TT 512
#define BB 64
#define II 256
#define HH 512
#define OO 64
#define NWG 256   // scan workgroups: one per CU (forced by LDS footprint)
#define TAGPAD 16 // dwords between tags (64B -> distinct LLC lines)

// DPP quad-perm cross-lane adds (VALU, not LDS pipe):
// xor1: perm [1,0,3,2] = 0xB1 ; xor2: perm [2,3,0,1] = 0x4E
__device__ __forceinline__ float xor1_dpp(float v) {
    return __int_as_float(__builtin_amdgcn_update_dpp(
        0, __float_as_int(v), 0xB1, 0xF, 0xF, true));
}
__device__ __forceinline__ float xor2_dpp(float v) {
    return __int_as_float(__builtin_amdgcn_update_dpp(
        0, __float_as_int(v), 0x4E, 0xF, 0xF, true));
}

// ---------------- Fused x-proj + XCD-local persistent GRU scan -----------
// r2-proven protocol (3 barriers, tid<32 LLC poll, plain h stores, B3 drain
// + tid0 release) + fused per-step x-projection:
//   top of step t: compute xp(t) from xlds (staged at t-1) using wxlds
//   (48KB x2h weights, LDS-resident) -> hides producers' release->discovery
//   latency under independent work; then poll -> B1 -> stage h -> B2 ->
//   (stage x(t+1) into xlds: reads of xlds all happened pre-B1, safe) ->
//   h-matvec -> reduce -> epilogue -> store h -> vmcnt(0) -> B3 -> release.
// Tags stay LLC-scope sc0 sc1 (round-3 lesson: L2-scope tags go stale-dirty
// across bench iterations). Reduce: cndmask-free lane-permuted transpose
// (rows r0=2s1+s0, r1=r0^2, r2=r0^1, r3=r0^3; weight col ^s2), with xor1/
// xor2 rounds on DPP (VALU) instead of ds_swizzle (LDS pipe relief).
__global__ __launch_bounds__(1024, 4)
void scan_kernel(const float* __restrict__ x,  const float* __restrict__ xw,
                 const float* __restrict__ xb, const float* __restrict__ hw,
                 const float* __restrict__ hbias, float* __restrict__ rnn,
                 int* __restrict__ tags)
{
    __shared__ float wxlds[48 * 256];   // 48KB: x2h weights, this WG's 16 cols
    __shared__ float hlds[8 * 512];     // 16KB: h(t-1), single buffer (r2)
    __shared__ float xlds[8 * 256];     // 8KB:  x(t)
    __shared__ float pad_[2304];        // ballast -> ~81.3KB -> 1 WG/CU
    __shared__ int s_rk;

    const int tid = threadIdx.x;
    ((volatile float*)pad_)[tid & 2047] = 0.f;  // keep ballast allocated

    int xcc;
    asm volatile("s_getreg_b32 %0, hwreg(HW_REG_XCC_ID)" : "=s"(xcc));
    const int g = xcc & 7;               // group = physical XCD
    if (tid == 0) {
        __threadfence();                 // one-time: drop stale/poison lines
        s_rk = atomicAdd(tags + NWG * TAGPAD + g * 16, 1); // rank in XCD
    }
    __syncthreads();
    const int rk = s_rk;
    if (rk >= 32) return;                // cannot happen with 1 WG/CU

    const int w    = tid >> 6;           // wave 0..15
    const int l    = tid & 63;           // lane
    const int cp   = w >> 1;             // column pair 0..7
    const int bh   = w & 1;              // batch half 0..1
    const int c0w  = rk * 16 + 2 * cp;   // wave's first column
    const int s0 = l & 1, s1 = (l >> 1) & 1, s2 = (l >> 2) & 1;
    const int col  = c0w + s2;                 // epilogue column (lanes l<8)
    const int ob   = 8 * g + 4 * bh + (l & 3); // epilogue batch row (global)

    // h staging map: thread stages 4 contiguous floats
    const int sb   = tid >> 7;
    const int sk   = (tid & 127) * 4;
    const int soff = sb * 512 + sk;
    const int hsoff = (8 * g + sb) * HH + sk;
    // x staging map: thread stages 2 contiguous floats
    const int sb2   = tid >> 7;
    const int sk2   = (tid & 127) * 2;
    const int soff2 = sb2 * 256 + sk2;
    const int xgoff = (8 * g + sb2) * II + sk2;

    // poll: lanes tid<32 poll rank-tid's tag (LLC); tid0 releases ours
    const int* tpoll = tags + ((size_t)g * 32 + (tid & 31)) * TAGPAD;
    int* tagme       = (int*)(tags + ((size_t)g * 32 + rk) * TAGPAD);

    // lane-permuted rows for cndmask-free transpose-reduce
    const int r0 = 2*s1 + s0, r1 = r0 ^ 2, r2 = r0 ^ 1, r3 = r0 ^ 3;
    const int roff0 = (4*bh + r0) * 512 + 4*l;
    const int roff1 = (4*bh + r1) * 512 + 4*l;
    const int roff2 = (4*bh + r2) * 512 + 4*l;
    const int roff3 = (4*bh + r3) * 512 + 4*l;
    const int xoff0 = (4*bh + r0) * 256 + 4*l;
    const int xoff1 = (4*bh + r1) * 256 + 4*l;
    const int xoff2 = (4*bh + r2) * 256 + 4*l;
    const int xoff3 = (4*bh + r3) * 256 + 4*l;
    // wx LDS row offsets for slot parity 0/1 (col = c0w + (parity^s2))
    const int wxA = (2*cp + s2)       * 256 + 4*l;  // parity 0
    const int wxB = (2*cp + (1 - s2)) * 256 + 4*l;  // parity 1

    // fill wxlds: rows gate*16+lc  <-  xw[(gate*512 + rk*16 + lc)][:]
    for (int idx = tid; idx < 48 * 64; idx += 1024) {
        int row = idx >> 6, c4 = (idx & 63) * 4;
        int gate = row >> 4, lc = row & 15;
        float4 v = *(const float4*)(xw + ((size_t)gate * 512 + rk * 16 + lc) * II + c4);
        *(float4*)(wxlds + row * 256 + c4) = v;
    }
    // stage x[0]
    {
        float2 v = *(const float2*)(x + xgoff);
        *(float2*)(xlds + soff2) = v;
    }

    // h2h weights -> registers: slot rr=2*gate+parity, col = c0w+(parity^s2)
    float wreg[6][8];
#pragma unroll
    for (int rr = 0; rr < 6; ++rr) {
        const float* wp = hw + ((size_t)(rr >> 1) * HH + c0w + ((rr & 1) ^ s2)) * HH;
        float4 a = *(const float4*)(wp + 4 * l);
        float4 b = *(const float4*)(wp + 256 + 4 * l);
        wreg[rr][0] = a.x; wreg[rr][1] = a.y; wreg[rr][2] = a.z; wreg[rr][3] = a.w;
        wreg[rr][4] = b.x; wreg[rr][5] = b.y; wreg[rr][6] = b.z; wreg[rr][7] = b.w;
    }
    const float bhr = hbias[col];
    const float bhu = hbias[HH + col];
    const float bhn = hbias[2 * HH + col];
    const float bxr = xb[col];
    const float bxu = xb[HH + col];
    const float bxn = xb[2 * HH + col];

    __syncthreads();   // wxlds + xlds ready

    float hloc = 0.f;            // lanes l<8: my (b,c) previous h (exact fp32)
    long long budget = 4000000;  // spin bound: bug -> wrong answer, not hang

    for (int t = 0; t < TT; ++t) {
        // prefetch x(t+1) into regs (LDS write deferred past barriers)
        const int tn = (t + 1 < TT) ? t + 1 : TT - 1;
        const float2 xnv = *(const float2*)(x + ((size_t)tn << 14) + xgoff);

        // ---- x-projection for step t (reads xlds staged last step) ----
        float4 xv0 = *(const float4*)(xlds + xoff0);
        float4 xv1 = *(const float4*)(xlds + xoff1);
        float4 xv2 = *(const float4*)(xlds + xoff2);
        float4 xv3 = *(const float4*)(xlds + xoff3);
        float xaA[6], xaB[6], xaC[6], xaD[6];
#pragma unroll
        for (int rr = 0; rr < 6; ++rr) {
            const float* wp = wxlds + (rr >> 1) * 4096 + ((rr & 1) ? wxB : wxA);
            float4 wx = *(const float4*)wp;
            xaA[rr] = fmaf(xv0.w, wx.w, fmaf(xv0.z, wx.z, fmaf(xv0.y, wx.y, xv0.x * wx.x)));
            xaB[rr] = fmaf(xv1.w, wx.w, fmaf(xv1.z, wx.z, fmaf(xv1.y, wx.y, xv1.x * wx.x)));
            xaC[rr] = fmaf(xv2.w, wx.w, fmaf(xv2.z, wx.z, fmaf(xv2.y, wx.y, xv2.x * wx.x)));
            xaD[rr] = fmaf(xv3.w, wx.w, fmaf(xv3.z, wx.z, fmaf(xv3.y, wx.y, xv3.x * wx.x)));
        }
        float xr, xu, xn;
        {
            float t0[6], t1[6], a2[6], a3[3];
#pragma unroll
            for (int rr = 0; rr < 6; ++rr) {
                t0[rr] = xaA[rr] + xor1_dpp(xaC[rr]);
                t1[rr] = xaB[rr] + xor1_dpp(xaD[rr]);
            }
#pragma unroll
            for (int rr = 0; rr < 6; ++rr)
                a2[rr] = t0[rr] + xor2_dpp(t1[rr]);
#pragma unroll
            for (int gt = 0; gt < 3; ++gt)
                a3[gt] = a2[2*gt] + __shfl_xor(a2[2*gt + 1], 4, 64);
#pragma unroll
            for (int gt = 0; gt < 3; ++gt) {
                a3[gt] += __shfl_xor(a3[gt], 8, 64);
                a3[gt] += __shfl_xor(a3[gt], 16, 64);
                a3[gt] += __shfl_xor(a3[gt], 32, 64);
            }
            xr = a3[0] + bxr; xu = a3[1] + bxu; xn = a3[2] + bxn;
        }

        float g0v = 0.f, g1v = 0.f, g2v = 0.f;
        if (t > 0) {
            // poll the 32 group tags (LLC; producers released step t-1)
            if (tid < 32) {
                int v;
                do {
                    asm volatile("global_load_dword %0, %1, off sc0 sc1\n\t"
                                 "s_waitcnt vmcnt(0)"
                                 : "=v"(v) : "v"(tpoll) : "memory");
                    if (v >= t) break;
                    __builtin_amdgcn_s_sleep(1);
                } while (--budget > 0);
            }
            __syncthreads(); // B1: h(t-1) complete in this XCD's L2

            // stage h(t-1) (16KB from L2)
            {
                const float* hs = rnn + ((size_t)(t - 1) << 15) + hsoff;
                *(float4*)(hlds + soff) = *(const float4*)hs;
            }
            __syncthreads(); // B2: staging complete

            // stage x(t+1): all xlds reads happened pre-B1 -> safe here
            *(float2*)(xlds + soff2) = xnv;

            // h-matvec: 4 b x 6 slots x 8 k = 192 FMA
            float4 hA0 = *(const float4*)(hlds + roff0), hB0 = *(const float4*)(hlds + roff0 + 256);
            float4 hA1 = *(const float4*)(hlds + roff1), hB1 = *(const float4*)(hlds + roff1 + 256);
            float4 hA2 = *(const float4*)(hlds + roff2), hB2 = *(const float4*)(hlds + roff2 + 256);
            float4 hA3 = *(const float4*)(hlds + roff3), hB3 = *(const float4*)(hlds + roff3 + 256);
            float accA[6], accB[6], accC[6], accD[6];
#pragma unroll
            for (int rr = 0; rr < 6; ++rr) {
                float a;
                a = hA0.x * wreg[rr][0];
                a = fmaf(hA0.y, wreg[rr][1], a); a = fmaf(hA0.z, wreg[rr][2], a);
                a = fmaf(hA0.w, wreg[rr][3], a); a = fmaf(hB0.x, wreg[rr][4], a);
                a = fmaf(hB0.y, wreg[rr][5], a); a = fmaf(hB0.z, wreg[rr][6], a);
                a = fmaf(hB0.w, wreg[rr][7], a);
                accA[rr] = a;
                a = hA1.x * wreg[rr][0];
                a = fmaf(hA1.y, wreg[rr][1], a); a = fmaf(hA1.z, wreg[rr][2], a);
                a = fmaf(hA1.w, wreg[rr][3], a); a = fmaf(hB1.x, wreg[rr][4], a);
                a = fmaf(hB1.y, wreg[rr][5], a); a = fmaf(hB1.z, wreg[rr][6], a);
                a = fmaf(hB1.w, wreg[rr][7], a);
                accB[rr] = a;
                a = hA2.x * wreg[rr][0];
                a = fmaf(hA2.y, wreg[rr][1], a); a = fmaf(hA2.z, wreg[rr][2], a);
                a = fmaf(hA2.w, wreg[rr][3], a); a = fmaf(hB2.x, wreg[rr][4], a);
                a = fmaf(hB2.y, wreg[rr][5], a); a = fmaf(hB2.z, wreg[rr][6], a);
                a = fmaf(hB2.w, wreg[rr][7], a);
                accC[rr] = a;
                a = hA3.x * wreg[rr][0];
                a = fmaf(hA3.y, wreg[rr][1], a); a = fmaf(hA3.z, wreg[rr][2], a);
                a = fmaf(hA3.w, wreg[rr][3], a); a = fmaf(hB3.x, wreg[rr][4], a);
                a = fmaf(hB3.y, wreg[rr][5], a); a = fmaf(hB3.z, wreg[rr][6], a);
                a = fmaf(hB3.w, wreg[rr][7], a);
                accD[rr] = a;
            }
            // cndmask-free transpose-reduce (xor1/2 on DPP)
            float t0[6], t1[6], a2[6], a3[3];
#pragma unroll
            for (int rr = 0; rr < 6; ++rr) {
                t0[rr] = accA[rr] + xor1_dpp(accC[rr]);
                t1[rr] = accB[rr] + xor1_dpp(accD[rr]);
            }
#pragma unroll
            for (int rr = 0; rr < 6; ++rr)
                a2[rr] = t0[rr] + xor2_dpp(t1[rr]);
#pragma unroll
            for (int gt = 0; gt < 3; ++gt)
                a3[gt] = a2[2*gt] + __shfl_xor(a2[2*gt + 1], 4, 64);
            g0v = a3[0]; g1v = a3[1]; g2v = a3[2];
            g0v += __shfl_xor(g0v, 8, 64); g0v += __shfl_xor(g0v, 16, 64); g0v += __shfl_xor(g0v, 32, 64);
            g1v += __shfl_xor(g1v, 8, 64); g1v += __shfl_xor(g1v, 16, 64); g1v += __shfl_xor(g1v, 32, 64);
            g2v += __shfl_xor(g2v, 8, 64); g2v += __shfl_xor(g2v, 16, 64); g2v += __shfl_xor(g2v, 32, 64);
        } else {
            __syncthreads(); // t=0: all xlds reads done -> safe to restage
            *(float2*)(xlds + soff2) = xnv;
        }

        if (l < 8) { // one lane per output (b=ob, c=col)
            float rg = 1.f / (1.f + __expf(-(xr + g0v + bhr)));
            float ug = 1.f / (1.f + __expf(-(xu + g1v + bhu)));
            // h2h bias of n-gate sits INSIDE reset*(...), per reference
            float npre = xn + rg * (g2v + bhn);
            float e  = __expf(-2.f * npre);
            float nv = 2.f / (1.f + e) - 1.f;
            float hy = ug * hloc + (1.f - ug) * nv;
            hloc = hy;
            float* dstp = rnn + ((size_t)t << 15) + ob * HH + col;
            // plain store: write-through into this XCD's L2
            asm volatile("global_store_dword %0, %1, off"
                         :: "v"(dstp), "v"(hy) : "memory");
        }
        asm volatile("s_waitcnt vmcnt(0)" ::: "memory"); // h stores drained
        __syncthreads(); // B3: all waves' stores + xlds restage complete
        if (tid == 0) {
            int tv = t + 1;
            asm volatile("global_store_dword %0, %1, off sc0 sc1"
                         :: "v"(tagme), "v"(tv) : "memory");
        }
    }
}

// ---------------- Phase C: fc output (unchanged) ----------------
__global__ __launch_bounds__(256)
void fc_kernel(const float* __restrict__ rnn, const float* __restrict__ fcw,
               const float* __restrict__ fcb, float* __restrict__ out)
{
    __shared__ float wlds[128][65];
    const int t = blockIdx.x;
    const int tid = threadIdx.x;
    const int o  = tid & 63;
    const int bg = tid >> 6;
    float acc[16];
#pragma unroll
    for (int i = 0; i < 16; ++i) acc[i] = 0.f;

    for (int kc = 0; kc < 4; ++kc) {
        const int k0 = kc * 128;
        __syncthreads();
        for (int idx = tid; idx < 64 * 32; idx += 256) {
            int oo = idx >> 5, kq = (idx & 31) * 4;
            float4 v = *(const float4*)(fcw + (size_t)oo * HH + k0 + kq);
            wlds[kq][oo] = v.x; wlds[kq+1][oo] = v.y;
            wlds[kq+2][oo] = v.z; wlds[kq+3][oo] = v.w;
        }
        __syncthreads();
#pragma unroll 2
        for (int k4 = 0; k4 < 32; ++k4) {
            float w0 = wlds[k4*4+0][o], w1 = wlds[k4*4+1][o];
            float w2 = wlds[k4*4+2][o], w3 = wlds[k4*4+3][o];
#pragma unroll
            for (int i = 0; i < 16; ++i) {
                int bb = bg * 16 + i;
                float4 h4 = *(const float4*)(rnn + ((size_t)t * BB + bb) * HH + k0 + k4*4);
                acc[i] = fmaf(h4.x, w0, fmaf(h4.y, w1, fmaf(h4.z, w2, fmaf(h4.w, w3, acc[i]))));
            }
        }
    }
    float bo = fcb[o];
#pragma unroll
    for (int i = 0; i < 16; ++i) {
        int bb = bg * 16 + i;
        out[((size_t)t * BB + bb) * OO + o] = acc[i] + bo;
    }
}

extern "C" void kernel_launch(void* const* d_in, const int* in_sizes, int n_in,
                              void* d_out, int out_size, void* d_ws, size_t ws_size,
                              hipStream_t stream)
{
    const float* x     = (const float*)d_in[0];
    const float* x2h_w = (const float*)d_in[1];
    const float* x2h_b = (const float*)d_in[2];
    const float* h2h_w = (const float*)d_in[3];
    const float* h2h_b = (const float*)d_in[4];
    const float* fc_w  = (const float*)d_in[5];
    const float* fc_b  = (const float*)d_in[6];

    float* out = (float*)d_out;                        // [T][B][O]
    float* rnn = (float*)d_out + (size_t)TT * BB * OO; // [T][B][H]

    int* tags = (int*)d_ws;                            // 256 WG tags + rank ctrs

    hipMemsetAsync(tags, 0, (NWG * TAGPAD + 8 * 16) * sizeof(int), stream);

    scan_kernel<<<NWG, 1024, 0, stream>>>(x, x2h_w, x2h_b, h2h_w, h2h_b, rnn, tags);
    fc_kernel<<<TT, 256, 0, stream>>>(rnn, fc_w, fc_b, out);
}